// Round 3
// baseline (123.326 us; speedup 1.0000x reference)
//
#include <hip/hip_runtime.h>

// DepthToSpace, BLOCK_SIZE=2
// in : x[B=16][C=256][H=128][W=128] f32   (C = (i*2+k)*64 + dd)
// out: y[B=16][d=64][2H=256][2W=256] f32
// out[b, dd, h*2+i, w*2+k] = x[b, (i*2+k)*64 + dd, h, w]
//
// Round-1 memory pattern (proven best):
//   per output quad t: float2 load from channel c0=i*128+dd, float2 from
//   c1=c0+64 (8B/lane, dense across lanes), one float4 store at quad t
//   (16B/lane, dense across lanes).
// Round-3 change: persistent grid-stride (2048 blocks), 32 quads/thread,
// unroll 4 -> 8 loads in flight per wave before first store, 128x fewer
// workgroup launches.

__global__ __launch_bounds__(256) void d2s_kernel(const float* __restrict__ x,
                                                  float* __restrict__ out,
                                                  int n4, int iters) {
    int t = blockIdx.x * blockDim.x + threadIdx.x;
    const int stride = gridDim.x * blockDim.x;
    float4* __restrict__ outv = reinterpret_cast<float4*>(out);

    #pragma unroll 4
    for (int it = 0; it < iters; ++it, t += stride) {
        // t = ((b*64 + dd)*256 + H)*64 + W4
        int W4 = t & 63;
        int H  = (t >> 6) & 255;
        int dd = (t >> 14) & 63;
        int b  = t >> 20;

        int h  = H >> 1;
        int i  = H & 1;
        int w0 = W4 << 1;

        int c0   = (i << 7) + dd;                          // k=0 channel; k=1 is +64
        int base = (b << 22) + (c0 << 14) + (h << 7) + w0; // ((b*256+c)*128+h)*128+w

        float2 a = *reinterpret_cast<const float2*>(x + base);              // k=0
        float2 c = *reinterpret_cast<const float2*>(x + base + (64 << 14)); // k=1

        float4 o;
        o.x = a.x; o.y = c.x; o.z = a.y; o.w = c.y;
        outv[t] = o;
    }
}

extern "C" void kernel_launch(void* const* d_in, const int* in_sizes, int n_in,
                              void* d_out, int out_size, void* d_ws, size_t ws_size,
                              hipStream_t stream) {
    const float* x = (const float*)d_in[0];
    float* out = (float*)d_out;
    int n4 = out_size / 4;                 // 16,777,216 output quads
    const int block = 256;
    const int grid  = 2048;                // 8 wg/CU on 256 CUs
    int stride = grid * block;             // 524288
    int iters = (n4 + stride - 1) / stride; // = 32 exactly
    d2s_kernel<<<grid, block, 0, stream>>>(x, out, n4, iters);
}

// Round 4
// 103.912 us; speedup vs baseline: 1.1868x; 1.1868x over previous
//
#include <hip/hip_runtime.h>

// DepthToSpace, BLOCK_SIZE=2
// in : x[B=16][C=256][H=128][W=128] f32   (C = (i*2+k)*64 + dd)
// out: y[B=16][d=64][2H=256][2W=256] f32
// out[b, dd, h*2+i, w*2+k] = x[b, (i*2+k)*64 + dd, h, w]
//
// R1 pattern (dense 8B loads x2, dense 16B store) + round-4 change:
// each thread handles 4 output quads spaced exactly 64 quads (one wave)
// apart. Every load/store instruction stays 100% dense across the wave,
// the wave's footprint is 8 full input rows + 4 KB contiguous output
// (page-local), and 8 independent loads are in flight before the first
// store -> 4x deeper memory pipeline, 4x fewer waves.

__global__ __launch_bounds__(256) void d2s_kernel(const float* __restrict__ x,
                                                  float* __restrict__ out) {
    int gtid = blockIdx.x * blockDim.x + threadIdx.x;
    int lane = gtid & 63;
    int wv   = gtid >> 6;
    int q0   = (wv << 8) + lane;          // wave covers quads [wv*256, wv*256+256)

    float4* __restrict__ outv = reinterpret_cast<float4*>(out);

    float2 a[4], c[4];
    #pragma unroll
    for (int j = 0; j < 4; ++j) {
        int q  = q0 + (j << 6);
        // q = ((b*64 + dd)*256 + H)*64 + W4
        int W4 = q & 63;
        int H  = (q >> 6) & 255;
        int dd = (q >> 14) & 63;
        int b  = q >> 20;

        int h  = H >> 1;
        int i  = H & 1;
        int w0 = W4 << 1;

        int c0   = (i << 7) + dd;                          // k=0 channel; k=1 is +64
        int base = (b << 22) + (c0 << 14) + (h << 7) + w0;

        a[j] = *reinterpret_cast<const float2*>(x + base);              // k=0
        c[j] = *reinterpret_cast<const float2*>(x + base + (64 << 14)); // k=1
    }

    #pragma unroll
    for (int j = 0; j < 4; ++j) {
        int q = q0 + (j << 6);
        float4 o;
        o.x = a[j].x; o.y = c[j].x; o.z = a[j].y; o.w = c[j].y;
        outv[q] = o;
    }
}

extern "C" void kernel_launch(void* const* d_in, const int* in_sizes, int n_in,
                              void* d_out, int out_size, void* d_ws, size_t ws_size,
                              hipStream_t stream) {
    const float* x = (const float*)d_in[0];
    float* out = (float*)d_out;
    int n4 = out_size / 4;                  // 16,777,216 output quads
    int threads = n4 / 4;                   // 4 quads per thread
    const int block = 256;
    int grid = threads / block;             // 16384 blocks, exact
    d2s_kernel<<<grid, block, 0, stream>>>(x, out);
}

// Round 5
// 97.865 us; speedup vs baseline: 1.2602x; 1.0618x over previous
//
#include <hip/hip_runtime.h>

// DepthToSpace, BLOCK_SIZE=2
// in : x[B=16][C=256][H=128][W=128] f32   (C = (i*2+k)*64 + dd)
// out: y[B=16][d=64][2H=256][2W=256] f32
// out[b, dd, h*2+i, w*2+k] = x[b, (i*2+k)*64 + dd, h, w]
//
// Round-5: copy-shaped instruction mix. One wave handles one output row
// (b,dd,H) = 256 floats. Even lanes load float4 from channel c0=i*128+dd,
// odd lanes from c1=c0+64 (one global_load_dwordx4: two dense 512B
// segments). Pair-exchange via 2x __shfl_xor(1), then each lane stores
// output quad (row*64 + lane): one dense 1KB global_store_dwordx4.
// Same bytes as R1, half the read instructions, copy-identical widths.

__global__ __launch_bounds__(256) void d2s_kernel(const float* __restrict__ x,
                                                  float* __restrict__ out) {
    int gtid = blockIdx.x * blockDim.x + threadIdx.x;
    int lane = gtid & 63;
    int wrow = gtid >> 6;              // output row id = (b*64 + dd)*256 + H

    int H  = wrow & 255;
    int dd = (wrow >> 8) & 63;
    int b  = wrow >> 14;

    int h  = H >> 1;
    int i  = H & 1;

    int s  = lane & 1;                 // 0 -> channel c0 (k=0), 1 -> c1 (k=1)
    int p  = lane >> 1;                // pair id: input w0 = 4p

    int ch   = (i << 7) + dd + (s << 6);
    int base = (b << 22) + (ch << 14) + (h << 7) + (p << 2);

    float4 v = *reinterpret_cast<const float4*>(x + base);

    // send partner what it needs: even sends z,w; odd sends x,y
    float m0 = s ? v.x : v.z;
    float m1 = s ? v.y : v.w;
    float r0 = __shfl_xor(m0, 1, 64);
    float r1 = __shfl_xor(m1, 1, 64);

    // even lane (quad 2p):   {v.x, r0, v.y, r1}   (r0=oth.x, r1=oth.y)
    // odd  lane (quad 2p+1): {r0, v.z, r1, v.w}   (r0=oth.z, r1=oth.w)
    float4 o;
    o.x = s ? r0  : v.x;
    o.y = s ? v.z : r0;
    o.z = s ? r1  : v.y;
    o.w = s ? v.w : r1;

    reinterpret_cast<float4*>(out)[(wrow << 6) + lane] = o;
}

extern "C" void kernel_launch(void* const* d_in, const int* in_sizes, int n_in,
                              void* d_out, int out_size, void* d_ws, size_t ws_size,
                              hipStream_t stream) {
    const float* x = (const float*)d_in[0];
    float* out = (float*)d_out;
    int n4 = out_size / 4;                  // 16,777,216 output quads
    const int block = 256;
    int grid = n4 / block;                  // 65536 blocks, exact
    d2s_kernel<<<grid, block, 0, stream>>>(x, out);
}

// Round 7
// 89.023 us; speedup vs baseline: 1.3853x; 1.0993x over previous
//
#include <hip/hip_runtime.h>

// DepthToSpace, BLOCK_SIZE=2
// in : x[B=16][C=256][H=128][W=128] f32   (C = (i*2+k)*64 + dd)
// out: y[B=16][d=64][2H=256][2W=256] f32
// out[b, dd, h*2+i, w*2+k] = x[b, (i*2+k)*64 + dd, h, w]
//
// Round-6b = Round-5 (copy-shaped: one dwordx4 load, shfl pair-exchange,
// one dense dwordx4 store per thread) + NON-TEMPORAL load/store hints,
// using clang ext_vector_type (HIP_vector_type rejected by the builtin).

typedef float f32x4 __attribute__((ext_vector_type(4)));

__global__ __launch_bounds__(256) void d2s_kernel(const float* __restrict__ x,
                                                  float* __restrict__ out) {
    int gtid = blockIdx.x * blockDim.x + threadIdx.x;
    int lane = gtid & 63;
    int wrow = gtid >> 6;              // output row id = (b*64 + dd)*256 + H

    int H  = wrow & 255;
    int dd = (wrow >> 8) & 63;
    int b  = wrow >> 14;

    int h  = H >> 1;
    int i  = H & 1;

    int s  = lane & 1;                 // 0 -> channel c0 (k=0), 1 -> c1 (k=1)
    int p  = lane >> 1;                // pair id: input w0 = 4p

    int ch   = (i << 7) + dd + (s << 6);
    int base = (b << 22) + (ch << 14) + (h << 7) + (p << 2);

    f32x4 v = __builtin_nontemporal_load(
        reinterpret_cast<const f32x4*>(x + base));

    // send partner what it needs: even sends z,w (v[2],v[3]); odd sends x,y
    float m0 = s ? v[0] : v[2];
    float m1 = s ? v[1] : v[3];
    float r0 = __shfl_xor(m0, 1, 64);
    float r1 = __shfl_xor(m1, 1, 64);

    // even lane (quad 2p):   {v0, r0, v1, r1}
    // odd  lane (quad 2p+1): {r0, v2, r1, v3}
    f32x4 o;
    o[0] = s ? r0   : v[0];
    o[1] = s ? v[2] : r0;
    o[2] = s ? r1   : v[1];
    o[3] = s ? v[3] : r1;

    __builtin_nontemporal_store(o,
        reinterpret_cast<f32x4*>(out) + (wrow << 6) + lane);
}

extern "C" void kernel_launch(void* const* d_in, const int* in_sizes, int n_in,
                              void* d_out, int out_size, void* d_ws, size_t ws_size,
                              hipStream_t stream) {
    const float* x = (const float*)d_in[0];
    float* out = (float*)d_out;
    int n4 = out_size / 4;                  // 16,777,216 output quads
    const int block = 256;
    int grid = n4 / block;                  // 65536 blocks, exact
    d2s_kernel<<<grid, block, 0, stream>>>(x, out);
}